// Round 9
// baseline (1449.360 us; speedup 1.0000x reference)
//
#include <hip/hip_runtime.h>
#include <hip/hip_bf16.h>

typedef __hip_bfloat16 bf16;
typedef __attribute__((ext_vector_type(8))) short bf16x8;
typedef __attribute__((ext_vector_type(4))) float floatx4;

__device__ __forceinline__ float b2f(bf16 v) { return __bfloat162float(v); }
__device__ __forceinline__ bf16 f2b(float v) { return __float2bfloat16(v); }
__device__ __forceinline__ float us2f(unsigned short u) {
  union { unsigned int i; float f; } v; v.i = ((unsigned int)u) << 16; return v.f;
}
__device__ __forceinline__ unsigned short f2us(float f) {
  bf16 h = f2b(f); return *(unsigned short*)&h;
}

// ---------------- global average pool: x (C,HW) fp32 NCHW -> gap[C] ------
__global__ __launch_bounds__(256) void gap_kernel(const float* __restrict__ x,
                                                  float* __restrict__ gap,
                                                  int HW, float inv) {
  int c = blockIdx.x;
  const float* p = x + (size_t)c * HW;
  float s = 0.f;
  for (int i = threadIdx.x; i < HW; i += 256) s += p[i];
  __shared__ float red[256];
  red[threadIdx.x] = s;
  __syncthreads();
  for (int w = 128; w > 0; w >>= 1) {
    if (threadIdx.x < w) red[threadIdx.x] += red[threadIdx.x + w];
    __syncthreads();
  }
  if (threadIdx.x == 0) gap[c] = red[0] * inv;
}

// -------- scale[o] = 1 + sigmoid( sum_i att_w[o,i] * gap[i] ) ------------
__global__ __launch_bounds__(256) void atten_kernel(const float* __restrict__ w,
                                                    const float* __restrict__ gap,
                                                    float* __restrict__ scale, int Ci) {
  int o = blockIdx.x * 256 + threadIdx.x;
  if (o >= Ci) return;
  const float* wr = w + (size_t)o * Ci;
  float s = 0.f;
  for (int i = 0; i < Ci; ++i) s += wr[i] * gap[i];
  scale[o] = 1.f + 1.f / (1.f + expf(-s));
}

// ---- bilinear 2x upsample NHWC(256)->NHWC(256); 4 px/block, 4 ch/thread --
__global__ __launch_bounds__(256) void upsample2x_nhwc_kernel(
    const bf16* __restrict__ src, bf16* __restrict__ dst, int Hs, int Ws) {
  int W = Ws * 2;
  int tid = threadIdx.x;
  int p = blockIdx.x * 4 + (tid >> 6);
  int c = (tid & 63) * 4;
  int y = p / W, x = p - y * W;
  float fy = y * 0.5f - 0.25f;
  float fx = x * 0.5f - 0.25f;
  int y0 = (int)floorf(fy), x0 = (int)floorf(fx);
  float wy1 = fy - (float)y0, wx1 = fx - (float)x0;
  int y0c = min(max(y0, 0), Hs - 1);
  int y1c = min(max(y0 + 1, 0), Hs - 1);
  int x0c = min(max(x0, 0), Ws - 1);
  int x1c = min(max(x0 + 1, 0), Ws - 1);
  ushort4 a00 = *(const ushort4*)&src[(size_t)(y0c * Ws + x0c) * 256 + c];
  ushort4 a01 = *(const ushort4*)&src[(size_t)(y0c * Ws + x1c) * 256 + c];
  ushort4 a10 = *(const ushort4*)&src[(size_t)(y1c * Ws + x0c) * 256 + c];
  ushort4 a11 = *(const ushort4*)&src[(size_t)(y1c * Ws + x1c) * 256 + c];
  float w00 = (1.f - wy1) * (1.f - wx1), w01 = (1.f - wy1) * wx1;
  float w10 = wy1 * (1.f - wx1), w11 = wy1 * wx1;
  ushort4 r;
  r.x = f2us(w00 * us2f(a00.x) + w01 * us2f(a01.x) + w10 * us2f(a10.x) + w11 * us2f(a11.x));
  r.y = f2us(w00 * us2f(a00.y) + w01 * us2f(a01.y) + w10 * us2f(a10.y) + w11 * us2f(a11.y));
  r.z = f2us(w00 * us2f(a00.z) + w01 * us2f(a01.z) + w10 * us2f(a10.z) + w11 * us2f(a11.z));
  r.w = f2us(w00 * us2f(a00.w) + w01 * us2f(a01.w) + w10 * us2f(a10.w) + w11 * us2f(a11.w));
  *(ushort4*)&dst[(size_t)p * 256 + c] = r;
}

// ------- pack GEMM weights (fp32 [256][K]) -> bf16 MFMA-B layout ---------
// BP[((k>>3)*256 + o)*8 + (k&7)] = w[o*K + k].  grid = K blocks.
__global__ __launch_bounds__(256) void packw1_kernel(const float* __restrict__ w,
                                                     bf16* __restrict__ BP, int K) {
  int idx = blockIdx.x * 256 + threadIdx.x;
  int j = idx & 7;
  int o = (idx >> 3) & 255;
  int kc8 = idx >> 11;
  int k = kc8 * 8 + j;
  BP[idx] = f2b(w[(size_t)o * K + k]);
}

// ------- pack dcn weights -> tap-major K'' = kt*256+ci, bf16 B layout ----
// BP[((k8)*256 + o)*8 + j] = w[o][ci=(k8*8+j)&255][kt=(k8*8+j)>>8]
__global__ __launch_bounds__(256) void packwd_kernel(const float* __restrict__ w,
                                                     bf16* __restrict__ BP) {
  int idx = blockIdx.x * 256 + threadIdx.x;   // grid 2304 -> 589824
  int j = idx & 7;
  int o = (idx >> 3) & 255;
  int k8 = idx >> 11;
  int kpp = k8 * 8 + j;
  int kt = kpp >> 8;
  int ci = kpp & 255;
  BP[idx] = f2b(w[(size_t)o * 2304 + ci * 9 + kt]);
}

// ------- pack 3x3 conv weights (fp32 OIHW, Ci=256) -> bf16 B layout ------
__global__ __launch_bounds__(256) void packw3_kernel(const float* __restrict__ w,
                                                     bf16* __restrict__ BP,
                                                     int Ci, int Co) {
  int idx = blockIdx.x * 256 + threadIdx.x;
  int total = Ci * 9 * 256;
  if (idx >= total) return;
  int j = idx & 7;
  int t1 = idx >> 3;
  int o = t1 & 255;
  int t2 = t1 >> 8;
  int q = t2 & 3;
  int t3 = t2 >> 2;
  int tap = t3 % 9;
  int c = t3 / 9;
  int ci = c * 32 + q * 8 + j;
  float v = (o < Co) ? w[((size_t)o * Ci + ci) * 9 + tap] : 0.f;
  BP[idx] = f2b(v);
}

// ------------- 1x1 conv as MFMA GEMM -------------------------------------
template <bool NCHW1, typename TA1>
__global__ __launch_bounds__(256) void conv1x1_mfma_kernel(
    const TA1* __restrict__ A1, const float* __restrict__ scaleA,
    const bf16* __restrict__ A2, float scaleB,
    int Ci1, int Ci2, int HW,
    const bf16* __restrict__ BP, const float* __restrict__ bias,
    float* __restrict__ out1, bf16* __restrict__ out2, int ns2) {
  __shared__ __align__(16) bf16 sA[1024];   // [4 q][32 px][8]
  int p0 = blockIdx.x * 32;
  int tid = threadIdx.x;
  int pix = tid & 31, sub = tid >> 5;       // fp32-NCHW staging mapping
  int pix2 = tid >> 3, sub8 = tid & 7;      // NHWC staging mapping
  int lane = tid & 63, wave = tid >> 6;
  int pg = wave & 1, cg = wave >> 1;
  int q = lane >> 4, n = lane & 15;

  floatx4 acc[4];
#pragma unroll
  for (int nt = 0; nt < 4; ++nt) acc[nt] = (floatx4)0.f;

  int nch = (Ci1 + Ci2) >> 5;
  for (int kc = 0; kc < nch; ++kc) {
    int ci0 = kc << 5;
    if (NCHW1 && ci0 < Ci1) {
#pragma unroll
      for (int it = 0; it < 4; ++it) {
        int cil = it * 8 + sub;
        float x = (float)A1[(size_t)(ci0 + cil) * HW + p0 + pix];
        if (scaleA) x *= scaleA[ci0 + cil];
        sA[((cil >> 3) * 32 + pix) * 8 + (cil & 7)] = f2b(x);
      }
    } else {
      const bf16* src; int cb; bool scl;
      if (!NCHW1 && ci0 < Ci1) {
        src = (const bf16*)(const void*)A1; cb = ci0; scl = false;
      } else {
        src = A2; cb = ci0 - Ci1; scl = true;
      }
      ushort4 raw = *(const ushort4*)&src[(size_t)(p0 + pix2) * 256 + cb + sub8 * 4];
      if (scl) {
        raw.x = f2us(us2f(raw.x) * scaleB);
        raw.y = f2us(us2f(raw.y) * scaleB);
        raw.z = f2us(us2f(raw.z) * scaleB);
        raw.w = f2us(us2f(raw.w) * scaleB);
      }
      *(ushort4*)&sA[((sub8 >> 1) * 32 + pix2) * 8 + (sub8 & 1) * 4] = raw;
    }
    __syncthreads();
    bf16x8 a = *(const bf16x8*)&sA[(q * 32 + pg * 16 + n) * 8];
    const bf16* bp = BP + ((size_t)(kc * 4 + q) * 256 + blockIdx.y * 128 + cg * 64) * 8;
#pragma unroll
    for (int nt = 0; nt < 4; ++nt) {
      bf16x8 b = *(const bf16x8*)&bp[(nt * 16 + n) * 8];
      acc[nt] = __builtin_amdgcn_mfma_f32_16x16x32_bf16(a, b, acc[nt], 0, 0, 0);
    }
    __syncthreads();
  }

  int pbase = p0 + pg * 16 + q * 4;
#pragma unroll
  for (int nt = 0; nt < 4; ++nt) {
    int o = blockIdx.y * 128 + cg * 64 + nt * 16 + n;
    float bv = bias ? bias[o] : 0.f;
#pragma unroll
    for (int r = 0; r < 4; ++r) {
      float v = acc[nt][r] + bv;
      if (out1) out1[(size_t)o * HW + pbase + r] = v;
      if (out2) out2[(size_t)(pbase + r) * ns2 + o] = f2b(v);
    }
  }
}

// ------------- 3x3 conv pad=1, MFMA implicit GEMM, NHWC(256) input -------
__global__ __launch_bounds__(256) void conv3x3_mfma_kernel(
    const bf16* __restrict__ in, const bf16* __restrict__ BP,
    const float* __restrict__ bias,
    int H, int W, int Co,
    float* __restrict__ out1, bf16* __restrict__ out2, int ns2) {
  __shared__ __align__(16) bf16 sA[9216];   // [9 tap][4 q][32 px][8]
  int HW = H * W;
  int segs = W >> 5;
  int y = blockIdx.x / segs;
  int x0 = (blockIdx.x - y * segs) << 5;
  int tid = threadIdx.x;
  int pix2 = tid >> 3, sub8 = tid & 7;
  int lane = tid & 63, wave = tid >> 6;
  int pg = wave & 1, cg = wave >> 1;
  int q = lane >> 4, n = lane & 15;

  floatx4 acc[4];
#pragma unroll
  for (int nt = 0; nt < 4; ++nt) acc[nt] = (floatx4)0.f;

  int xx = x0 + pix2;
  for (int kc = 0; kc < 8; ++kc) {
    int ci0 = kc << 5;
#pragma unroll
    for (int tap = 0; tap < 9; ++tap) {
      int dy = tap / 3 - 1, dx = tap % 3 - 1;
      int yy = y + dy, xg = xx + dx;
      ushort4 v = {0, 0, 0, 0};
      if ((unsigned)yy < (unsigned)H && (unsigned)xg < (unsigned)W)
        v = *(const ushort4*)&in[(size_t)(yy * W + xg) * 256 + ci0 + sub8 * 4];
      *(ushort4*)&sA[((tap * 4 + (sub8 >> 1)) * 32 + pix2) * 8 + (sub8 & 1) * 4] = v;
    }
    __syncthreads();
    const bf16* bpc = BP + (size_t)kc * 73728;
#pragma unroll
    for (int tap = 0; tap < 9; ++tap) {
      bf16x8 a = *(const bf16x8*)&sA[((tap * 4 + q) * 32 + pg * 16 + n) * 8];
      const bf16* bp =
          bpc + ((size_t)(tap * 4 + q) * 256 + blockIdx.y * 128 + cg * 64) * 8;
#pragma unroll
      for (int nt = 0; nt < 4; ++nt) {
        bf16x8 b = *(const bf16x8*)&bp[(nt * 16 + n) * 8];
        acc[nt] = __builtin_amdgcn_mfma_f32_16x16x32_bf16(a, b, acc[nt], 0, 0, 0);
      }
    }
    __syncthreads();
  }

  int pbase = y * W + x0 + pg * 16 + q * 4;
#pragma unroll
  for (int nt = 0; nt < 4; ++nt) {
    int o = blockIdx.y * 128 + cg * 64 + nt * 16 + n;
    if (o < Co) {
      float bv = bias ? bias[o] : 0.f;
#pragma unroll
      for (int r = 0; r < 4; ++r) {
        float v = acc[nt][r] + bv;
        if (out1) out1[(size_t)o * HW + pbase + r] = v;
        if (out2) out2[(size_t)(pbase + r) * ns2 + o] = f2b(v);
      }
    }
  }
}

// ---- mdcn v3: 16-px tile, tap-major K'', NHWC gather + MFMA dot ----------
// UPn: NHWC(256); OM: NHWC(216); BPd: packwd (K''=kt*256+ci);
// ARM/F: NHWC(256). grid = HW/16.
#define MROW 136  // 16*8 + 8 pad: +4-bank shift/row -> conflict-free writes
__global__ __launch_bounds__(256) void mdcn_mfma_kernel(
    const bf16* __restrict__ UPn, const bf16* __restrict__ OM,
    const bf16* __restrict__ BPd, const float* __restrict__ dcn_b,
    const bf16* __restrict__ ARM, bf16* __restrict__ F,
    int H, int W, int wshift) {
  __shared__ __align__(16) bf16 sval[288 * MROW];  // 78336 B
  int pb = blockIdx.x * 16;
  int tid = threadIdx.x;
  int l = tid & 31;       // channel-in-group
  int grp = tid >> 5;     // 0..7 = deformable group g
  int g = grp;
  for (int px = 0; px < 16; ++px) {
    int p = pb + px;
    int y = p >> wshift, x = p & (W - 1);
    const bf16* omp = OM + (size_t)p * 216;
    const bf16* upg = UPn + g * 32 + l;
#pragma unroll
    for (int kt = 0; kt < 9; ++kt) {
      float dy = b2f(omp[g * 18 + kt]);
      float dx = b2f(omp[g * 18 + 9 + kt]);
      float mm = 1.f / (1.f + expf(-b2f(omp[144 + g * 9 + kt])));
      float fpy = (float)(y - 1 + kt / 3) + dy;
      float fpx = (float)(x - 1 + kt % 3) + dx;
      fpy = fminf(fmaxf(fpy, -1.0e4f), 1.0e4f);
      fpx = fminf(fmaxf(fpx, -1.0e4f), 1.0e4f);
      float fy0 = floorf(fpy), fx0 = floorf(fpx);
      float wy1 = fpy - fy0, wx1 = fpx - fx0;
      int iy0 = (int)fy0, ix0 = (int)fx0;
      bool vy0 = ((unsigned)iy0 < (unsigned)H);
      bool vy1 = ((unsigned)(iy0 + 1) < (unsigned)H);
      bool vx0 = ((unsigned)ix0 < (unsigned)W);
      bool vx1 = ((unsigned)(ix0 + 1) < (unsigned)W);
      const bf16* up = upg + (size_t)(iy0 * W + ix0) * 256;
      float v00 = (vy0 && vx0) ? b2f(up[0]) : 0.f;
      float v01 = (vy0 && vx1) ? b2f(up[256]) : 0.f;
      float v10 = (vy1 && vx0) ? b2f(up[(size_t)W * 256]) : 0.f;
      float v11 = (vy1 && vx1) ? b2f(up[(size_t)W * 256 + 256]) : 0.f;
      float sv = mm * ((1.f - wy1) * ((1.f - wx1) * v00 + wx1 * v01)
                     + wy1 * ((1.f - wx1) * v10 + wx1 * v11));
      // K'' = kt*256 + g*32 + l -> row = K''>>3, j = K''&7 = l&7
      int row = kt * 32 + g * 4 + (l >> 3);
      sval[row * MROW + px * 8 + (l & 7)] = f2b(sv);
    }
  }
  __syncthreads();

  int lane = tid & 63, wave = tid >> 6;
  int q = lane >> 4, n = lane & 15;
  floatx4 acc[4];
#pragma unroll
  for (int nt = 0; nt < 4; ++nt) acc[nt] = (floatx4)0.f;
  for (int kc = 0; kc < 72; ++kc) {
    bf16x8 a = *(const bf16x8*)&sval[(kc * 4 + q) * MROW + n * 8];
    const bf16* bp = BPd + ((size_t)(kc * 4 + q) * 256 + wave * 64) * 8;
#pragma unroll
    for (int nt = 0; nt < 4; ++nt) {
      bf16x8 b = *(const bf16x8*)&bp[(nt * 16 + n) * 8];
      acc[nt] = __builtin_amdgcn_mfma_f32_16x16x32_bf16(a, b, acc[nt], 0, 0, 0);
    }
  }
  int pbase = pb + q * 4;
#pragma unroll
  for (int nt = 0; nt < 4; ++nt) {
    int o = wave * 64 + nt * 16 + n;
    float bv = dcn_b[o];
#pragma unroll
    for (int r = 0; r < 4; ++r) {
      int p = pbase + r;
      float v = fmaxf(acc[nt][r] + bv, 0.f) + b2f(ARM[(size_t)p * 256 + o]);
      F[(size_t)p * 256 + o] = f2b(v);
    }
  }
}

extern "C" void kernel_launch(void* const* d_in, const int* in_sizes, int n_in,
                              void* d_out, int out_size, void* d_ws, size_t ws_size,
                              hipStream_t stream) {
  // Inputs fp32, outputs fp32 (established rounds 3-5). Interior: bf16 NHWC.
  const float* c2 = (const float*)d_in[0];
  const float* c3 = (const float*)d_in[1];
  const float* c4 = (const float*)d_in[2];
  const float* c5 = (const float*)d_in[3];
  const float* lat_w = (const float*)d_in[31];
  const float* lat_b = (const float*)d_in[32];
  float* out = (float*)d_out;
  (void)ws_size; (void)in_sizes; (void)n_in; (void)out_size;

  const size_t p2_off = 0;
  const size_t p3_off = 4194304;
  const size_t p4_off = p3_off + 1048576;
  const size_t p5_off = p4_off + 262144;

  // ---- ws layout (~26.5MB; ws_size >= 28MB proven round 3) ----
  char* ws = (char*)d_ws;
  bf16* UPn = (bf16*)(ws);                    // 8MB NHWC
  bf16* ARM = (bf16*)(ws + 8388608);          // 8MB NHWC
  bf16* FB  = (bf16*)(ws + 16777216);         // 8MB NHWC (off_feat & F alias)
  bf16* P5N = (bf16*)(ws + 25165824);         // 128KB NHWC p5 copy
  bf16* BPB = (bf16*)(ws + 25296896);         // 1.125MB packed-B scratch
  float* GAP = (float*)(ws + 26476544);
  float* SC  = (float*)(ws + 26484736);
  // OM (NHWC stride 216) borrows the p2 output region; p2 is written only by
  // the final conv, after mdcn consumed OM.
  bf16* OM = (bf16*)(out + p2_off);

  // ---- p5 = conv1x1(c5, lat_w, lat_b): fp32 NCHW out + bf16 NHWC copy ----
  packw1_kernel<<<2048, 256, 0, stream>>>(lat_w, BPB, 2048);
  conv1x1_mfma_kernel<true, float><<<dim3(8, 2), 256, 0, stream>>>(
      c5, nullptr, nullptr, 0.f, 2048, 0, 256, BPB, lat_b,
      out + p5_off, P5N, 256);

  struct Lv {
    const float* featl; int Ci; int H; int W; int wshift;
    float* pdst; int wbase;
  };
  Lv levels[3] = {
      {c4, 1024, 32, 32, 5, out + p4_off, 4},
      {c3, 512, 64, 64, 6, out + p3_off, 13},
      {c2, 256, 128, 128, 7, out + p2_off, 22},
  };

  for (int li = 0; li < 3; ++li) {
    const Lv& L = levels[li];
    const float* att_w = (const float*)d_in[L.wbase + 0];
    const float* fsm_w = (const float*)d_in[L.wbase + 1];
    const float* off_w = (const float*)d_in[L.wbase + 2];
    const float* om_w  = (const float*)d_in[L.wbase + 3];
    const float* om_b  = (const float*)d_in[L.wbase + 4];
    const float* dcn_w = (const float*)d_in[L.wbase + 5];
    const float* dcn_b = (const float*)d_in[L.wbase + 6];
    const float* out_w = (const float*)d_in[L.wbase + 7];
    const float* out_b = (const float*)d_in[L.wbase + 8];
    int HW = L.H * L.W;

    // 1) feat_up = bilinear 2x (NHWC): src = P5N or previous F (FB)
    upsample2x_nhwc_kernel<<<HW / 4, 256, 0, stream>>>(
        (li == 0) ? P5N : FB, UPn, L.H / 2, L.W / 2);
    // 2) FSM: gap -> atten -> scaled 1x1 GEMM -> ARM (NHWC)
    gap_kernel<<<L.Ci, 256, 0, stream>>>(L.featl, GAP, HW, 1.f / (float)HW);
    atten_kernel<<<L.Ci / 256, 256, 0, stream>>>(att_w, GAP, SC, L.Ci);
    packw1_kernel<<<L.Ci, 256, 0, stream>>>(fsm_w, BPB, L.Ci);
    conv1x1_mfma_kernel<true, float><<<dim3(HW / 32, 2), 256, 0, stream>>>(
        L.featl, SC, nullptr, 0.f, L.Ci, 0, HW, BPB, nullptr,
        nullptr, ARM, 256);
    // 3) off_feat = conv1x1(concat(ARM, 2*UPn)) -> FB (NHWC)
    packw1_kernel<<<512, 256, 0, stream>>>(off_w, BPB, 512);
    conv1x1_mfma_kernel<false, bf16><<<dim3(HW / 32, 2), 256, 0, stream>>>(
        ARM, nullptr, UPn, 2.f, 256, 256, HW, BPB, nullptr,
        nullptr, FB, 256);
    // 4) om = conv3x3(FB) + om_b -> OM (NHWC stride 216, in p2 region)
    packw3_kernel<<<2304, 256, 0, stream>>>(om_w, BPB, 256, 216);
    conv3x3_mfma_kernel<<<dim3(HW / 32, 2), 256, 0, stream>>>(
        FB, BPB, om_b, L.H, L.W, 216, nullptr, OM, 216);
    // 5) F = relu(mdcn(UPn, OM) + dcn_b) + ARM -> FB (NHWC)
    packwd_kernel<<<2304, 256, 0, stream>>>(dcn_w, BPB);
    mdcn_mfma_kernel<<<HW / 16, 256, 0, stream>>>(
        UPn, OM, BPB, dcn_b, ARM, FB, L.H, L.W, L.wshift);
    // 6) p = conv3x3(F) + out_b -> fp32 NCHW output
    packw3_kernel<<<2304, 256, 0, stream>>>(out_w, BPB, 256, 256);
    conv3x3_mfma_kernel<<<dim3(HW / 32, 2), 256, 0, stream>>>(
        FB, BPB, out_b, L.H, L.W, 256, L.pdst, nullptr, 256);
  }
}